// Round 1
// baseline (3214.713 us; speedup 1.0000x reference)
//
#include <hip/hip_runtime.h>

#define N_NODES 50000
#define E_EDGES 800000
#define R_REL 3
#define DH 128
#define BATCHES 256
#define NCLASS 10
#define EPSV 1e-5f

// ---------------------------------------------------------------- build x
__global__ void build_x_kernel(const int* __restrict__ xi,
                               const float* __restrict__ se,
                               const float* __restrict__ ce,
                               const float* __restrict__ pe,
                               float* __restrict__ x) {
    int tid = blockIdx.x * blockDim.x + threadIdx.x;   // N*32 threads
    int node = tid >> 5, c = tid & 31;
    if (node >= N_NODES) return;
    int i0 = xi[node * 3 + 0];
    int i1 = xi[node * 3 + 1];
    int i2 = xi[node * 3 + 2];
    i2 = i2 < 0 ? 0 : (i2 > 24 ? 24 : i2);
    const float4 a = *reinterpret_cast<const float4*>(se + (size_t)i0 * DH + c * 4);
    const float4 b = *reinterpret_cast<const float4*>(ce + (size_t)i1 * DH + c * 4);
    const float4 p = *reinterpret_cast<const float4*>(pe + (size_t)i2 * DH + c * 4);
    float4 o;
    o.x = a.x + b.x + p.x; o.y = a.y + b.y + p.y;
    o.z = a.z + b.z + p.z; o.w = a.w + b.w + p.w;
    *reinterpret_cast<float4*>(x + (size_t)node * DH + c * 4) = o;
}

// ---------------------------------------------------------------- edge counts
__global__ void count_kernel(const int* __restrict__ ei,
                             const int* __restrict__ et,
                             float* __restrict__ C) {
    int e = blockIdx.x * blockDim.x + threadIdx.x;
    if (e >= E_EDGES) return;
    int dst = ei[E_EDGES + e];
    int r = et[e];
    atomicAdd(&C[dst * R_REL + r], 1.0f);
}

// ---------------------------------------------------------------- scatter x[src] into S[(dst,rel)]
__global__ void scatter_kernel(const float* __restrict__ xin,
                               const int* __restrict__ ei,
                               const int* __restrict__ et,
                               float* __restrict__ S) {
    int tid = blockIdx.x * blockDim.x + threadIdx.x;   // E*32 threads
    int e = tid >> 5, c = tid & 31;
    if (e >= E_EDGES) return;
    int src = ei[e];
    int dst = ei[E_EDGES + e];
    int r = et[e];
    const float4 v = *reinterpret_cast<const float4*>(xin + (size_t)src * DH + c * 4);
    float* p = S + ((size_t)dst * R_REL + r) * DH + c * 4;
    atomicAdd(p + 0, v.x);
    atomicAdd(p + 1, v.y);
    atomicAdd(p + 2, v.z);
    atomicAdd(p + 3, v.w);
}

// ---------------------------------------------------------------- fused mean-GEMM + BN(eval) + ReLU
// out[n,h] = relu( scale[h]*(sum_r (S[n,r,:]/cnt) @ W[r] + x @ root + b[h] - m[h]) + beta[h] )
// Tile: 32 nodes x 128 cols per block (256 threads). K=512 in 4 chunks of 128.
__global__ __launch_bounds__(256) void rgcn_gemm_bn_relu(
        const float* __restrict__ S, const float* __restrict__ C,
        const float* __restrict__ xin, const float* __restrict__ W,
        const float* __restrict__ root, const float* __restrict__ bias,
        const float* __restrict__ g, const float* __restrict__ beta,
        const float* __restrict__ m, const float* __restrict__ v,
        float* __restrict__ out) {
    __shared__ float Ash[DH][36];   // [d][node], pad 36 keeps float4 rows 16B-aligned
    const int n0 = blockIdx.x * 32;
    const int t = threadIdx.x;
    const int cg = t >> 3;    // 0..31 -> columns cg*4..+4
    const int ngp = t & 7;    // 0..7  -> nodes ngp*4..+4

    float acc00 = 0, acc01 = 0, acc02 = 0, acc03 = 0;
    float acc10 = 0, acc11 = 0, acc12 = 0, acc13 = 0;
    float acc20 = 0, acc21 = 0, acc22 = 0, acc23 = 0;
    float acc30 = 0, acc31 = 0, acc32 = 0, acc33 = 0;

    for (int k = 0; k < 4; ++k) {
        __syncthreads();
        // stage chunk: thread -> node i = t>>3, d range dq..dq+16
        {
            int i = t >> 3;
            int dq = (t & 7) * 16;
            int n = n0 + i;
            if (n < N_NODES) {
                if (k < 3) {
                    float cnt = C[(size_t)n * R_REL + k];
                    float inv = cnt > 0.f ? 1.f / cnt : 0.f;
                    const float4* srcp = reinterpret_cast<const float4*>(
                        S + ((size_t)n * R_REL + k) * DH + dq);
                    #pragma unroll
                    for (int j = 0; j < 4; ++j) {
                        float4 val = srcp[j];
                        int d0 = dq + j * 4;
                        Ash[d0 + 0][i] = val.x * inv;
                        Ash[d0 + 1][i] = val.y * inv;
                        Ash[d0 + 2][i] = val.z * inv;
                        Ash[d0 + 3][i] = val.w * inv;
                    }
                } else {
                    const float4* srcp = reinterpret_cast<const float4*>(
                        xin + (size_t)n * DH + dq);
                    #pragma unroll
                    for (int j = 0; j < 4; ++j) {
                        float4 val = srcp[j];
                        int d0 = dq + j * 4;
                        Ash[d0 + 0][i] = val.x;
                        Ash[d0 + 1][i] = val.y;
                        Ash[d0 + 2][i] = val.z;
                        Ash[d0 + 3][i] = val.w;
                    }
                }
            } else {
                #pragma unroll
                for (int j = 0; j < 4; ++j) {
                    int d0 = dq + j * 4;
                    Ash[d0 + 0][i] = 0.f; Ash[d0 + 1][i] = 0.f;
                    Ash[d0 + 2][i] = 0.f; Ash[d0 + 3][i] = 0.f;
                }
            }
        }
        __syncthreads();

        const float* Wk = (k < 3) ? (W + (size_t)k * DH * DH) : root;
        #pragma unroll 8
        for (int d = 0; d < DH; ++d) {
            const float4 a4 = *reinterpret_cast<const float4*>(&Ash[d][ngp * 4]);
            const float4 w4 = *reinterpret_cast<const float4*>(Wk + (size_t)d * DH + cg * 4);
            acc00 += a4.x * w4.x; acc01 += a4.x * w4.y; acc02 += a4.x * w4.z; acc03 += a4.x * w4.w;
            acc10 += a4.y * w4.x; acc11 += a4.y * w4.y; acc12 += a4.y * w4.z; acc13 += a4.y * w4.w;
            acc20 += a4.z * w4.x; acc21 += a4.z * w4.y; acc22 += a4.z * w4.z; acc23 += a4.z * w4.w;
            acc30 += a4.w * w4.x; acc31 += a4.w * w4.y; acc32 += a4.w * w4.z; acc33 += a4.w * w4.w;
        }
    }

    // epilogue: BN(eval) + ReLU
    int hb = cg * 4;
    float sc0 = g[hb + 0] * rsqrtf(v[hb + 0] + EPSV);
    float sc1 = g[hb + 1] * rsqrtf(v[hb + 1] + EPSV);
    float sc2 = g[hb + 2] * rsqrtf(v[hb + 2] + EPSV);
    float sc3 = g[hb + 3] * rsqrtf(v[hb + 3] + EPSV);
    float sh0 = (bias[hb + 0] - m[hb + 0]) * sc0 + beta[hb + 0];
    float sh1 = (bias[hb + 1] - m[hb + 1]) * sc1 + beta[hb + 1];
    float sh2 = (bias[hb + 2] - m[hb + 2]) * sc2 + beta[hb + 2];
    float sh3 = (bias[hb + 3] - m[hb + 3]) * sc3 + beta[hb + 3];

    float accs[4][4] = {
        {acc00, acc01, acc02, acc03},
        {acc10, acc11, acc12, acc13},
        {acc20, acc21, acc22, acc23},
        {acc30, acc31, acc32, acc33}};
    #pragma unroll
    for (int i = 0; i < 4; ++i) {
        int n = n0 + ngp * 4 + i;
        if (n < N_NODES) {
            float4 o;
            o.x = fmaxf(accs[i][0] * sc0 + sh0, 0.f);
            o.y = fmaxf(accs[i][1] * sc1 + sh1, 0.f);
            o.z = fmaxf(accs[i][2] * sc2 + sh2, 0.f);
            o.w = fmaxf(accs[i][3] * sc3 + sh3, 0.f);
            *reinterpret_cast<float4*>(out + (size_t)n * DH + hb) = o;
        }
    }
}

// ---------------------------------------------------------------- global mean pool (sum part)
__global__ void pool_kernel(const float* __restrict__ h,
                            const int* __restrict__ batch,
                            float* __restrict__ pool,
                            int* __restrict__ pcnt) {
    int tid = blockIdx.x * blockDim.x + threadIdx.x;   // N*32 threads
    int node = tid >> 5, c = tid & 31;
    if (node >= N_NODES) return;
    int b = batch[node];
    const float4 v = *reinterpret_cast<const float4*>(h + (size_t)node * DH + c * 4);
    float* p = pool + (size_t)b * DH + c * 4;
    atomicAdd(p + 0, v.x);
    atomicAdd(p + 1, v.y);
    atomicAdd(p + 2, v.z);
    atomicAdd(p + 3, v.w);
    if (c == 0) atomicAdd(&pcnt[b], 1);
}

// ---------------------------------------------------------------- classifier
__global__ void classify_kernel(const float* __restrict__ pool,
                                const int* __restrict__ pcnt,
                                const float* __restrict__ clsW,
                                const float* __restrict__ clsb,
                                float* __restrict__ out) {
    int tid = blockIdx.x * blockDim.x + threadIdx.x;
    if (tid >= BATCHES * NCLASS) return;
    int b = tid / NCLASS, c = tid % NCLASS;
    float cnt = (float)pcnt[b];
    float inv = cnt > 0.f ? 1.f / cnt : 1.f;
    const float* pr = pool + (size_t)b * DH;
    float s = 0.f;
    #pragma unroll 8
    for (int h = 0; h < DH; ++h) s += pr[h] * clsW[h * NCLASS + c];
    out[tid] = s * inv + clsb[c];
}

// ---------------------------------------------------------------- launch
extern "C" void kernel_launch(void* const* d_in, const int* in_sizes, int n_in,
                              void* d_out, int out_size, void* d_ws, size_t ws_size,
                              hipStream_t stream) {
    const int*   x_idx  = (const int*)d_in[0];
    const int*   eidx   = (const int*)d_in[1];
    const int*   etype  = (const int*)d_in[2];
    const int*   batch  = (const int*)d_in[3];
    const float* se     = (const float*)d_in[4];
    const float* ce     = (const float*)d_in[5];
    const float* pe     = (const float*)d_in[6];
    const float* W1     = (const float*)d_in[7];
    const float* root1  = (const float*)d_in[8];
    const float* b1     = (const float*)d_in[9];
    const float* g1     = (const float*)d_in[10];
    const float* beta1  = (const float*)d_in[11];
    const float* m1     = (const float*)d_in[12];
    const float* v1     = (const float*)d_in[13];
    const float* W2     = (const float*)d_in[14];
    const float* root2  = (const float*)d_in[15];
    const float* b2     = (const float*)d_in[16];
    const float* g2     = (const float*)d_in[17];
    const float* beta2  = (const float*)d_in[18];
    const float* m2     = (const float*)d_in[19];
    const float* v2     = (const float*)d_in[20];
    const float* clsW   = (const float*)d_in[21];
    const float* clsb   = (const float*)d_in[22];
    float* out = (float*)d_out;

    // workspace layout
    char* ws = (char*)d_ws;
    const size_t S_bytes    = (size_t)N_NODES * R_REL * DH * 4;   // 76,800,000
    const size_t C_bytes    = (size_t)N_NODES * R_REL * 4;        //    600,000
    const size_t X_bytes    = (size_t)N_NODES * DH * 4;           // 25,600,000
    const size_t pool_bytes = (size_t)BATCHES * DH * 4;           //    131,072
    float* S    = (float*)(ws);
    float* C    = (float*)(ws + S_bytes);
    float* xbuf = (float*)(ws + S_bytes + C_bytes);
    float* pool = (float*)(ws + S_bytes + C_bytes + X_bytes);
    int*   pcnt = (int*)(ws + S_bytes + C_bytes + X_bytes + pool_bytes);

    // zero S + C (contiguous) and pool + pcnt (contiguous)
    hipMemsetAsync(S, 0, S_bytes + C_bytes, stream);
    hipMemsetAsync(pool, 0, pool_bytes + BATCHES * 4, stream);

    const int TB = 256;
    // x = shape + color + pos embeddings
    build_x_kernel<<<(N_NODES * 32 + TB - 1) / TB, TB, 0, stream>>>(x_idx, se, ce, pe, xbuf);
    // per-(dst,rel) edge counts (shared by both layers)
    count_kernel<<<(E_EDGES + TB - 1) / TB, TB, 0, stream>>>(eidx, etype, C);

    // ----- layer 1
    scatter_kernel<<<(E_EDGES * 32 + TB - 1) / TB, TB, 0, stream>>>(xbuf, eidx, etype, S);
    rgcn_gemm_bn_relu<<<(N_NODES + 31) / 32, TB, 0, stream>>>(
        S, C, xbuf, W1, root1, b1, g1, beta1, m1, v1, xbuf);   // h1 aliases xbuf (block-local rows)

    // ----- layer 2
    hipMemsetAsync(S, 0, S_bytes, stream);
    scatter_kernel<<<(E_EDGES * 32 + TB - 1) / TB, TB, 0, stream>>>(xbuf, eidx, etype, S);
    rgcn_gemm_bn_relu<<<(N_NODES + 31) / 32, TB, 0, stream>>>(
        S, C, xbuf, W2, root2, b2, g2, beta2, m2, v2, xbuf);   // h2 aliases xbuf

    // ----- global mean pool + classifier
    pool_kernel<<<(N_NODES * 32 + TB - 1) / TB, TB, 0, stream>>>(xbuf, batch, pool, pcnt);
    classify_kernel<<<(BATCHES * NCLASS + TB - 1) / TB, TB, 0, stream>>>(
        pool, pcnt, clsW, clsb, out);
}

// Round 2
// 676.412 us; speedup vs baseline: 4.7526x; 4.7526x over previous
//
#include <hip/hip_runtime.h>

#define N_NODES 50000
#define E_EDGES 800000
#define R_REL 3
#define DH 128
#define AST (4 * DH)          // A row stride: [mean_r0 | mean_r1 | mean_r2 | x/h]
#define BATCHES 256
#define NCLASS 10
#define EPSV 1e-5f
#define SCAN_BLOCKS ((N_NODES + 255) / 256)   // 196

// ---------------------------------------------------------------- build x into A[n][3]
__global__ void build_x_kernel(const int* __restrict__ xi,
                               const float* __restrict__ se,
                               const float* __restrict__ ce,
                               const float* __restrict__ pe,
                               float* __restrict__ A) {
    int tid = blockIdx.x * blockDim.x + threadIdx.x;   // N*32 threads
    int node = tid >> 5, c = tid & 31;
    if (node >= N_NODES) return;
    int i0 = xi[node * 3 + 0];
    int i1 = xi[node * 3 + 1];
    int i2 = xi[node * 3 + 2];
    i2 = i2 < 0 ? 0 : (i2 > 24 ? 24 : i2);
    const float4 a = *reinterpret_cast<const float4*>(se + (size_t)i0 * DH + c * 4);
    const float4 b = *reinterpret_cast<const float4*>(ce + (size_t)i1 * DH + c * 4);
    const float4 p = *reinterpret_cast<const float4*>(pe + (size_t)i2 * DH + c * 4);
    float4 o;
    o.x = a.x + b.x + p.x; o.y = a.y + b.y + p.y;
    o.z = a.z + b.z + p.z; o.w = a.w + b.w + p.w;
    *reinterpret_cast<float4*>(A + (size_t)node * AST + 3 * DH + c * 4) = o;
}

// ---------------------------------------------------------------- CSR: per-dst degree
__global__ void count_dst_kernel(const int* __restrict__ ei, int* __restrict__ cnt) {
    int e = blockIdx.x * blockDim.x + threadIdx.x;
    if (e >= E_EDGES) return;
    atomicAdd(&cnt[ei[E_EDGES + e]], 1);
}

// ---------------------------------------------------------------- CSR: hierarchical exclusive scan
__global__ void scan1_kernel(const int* __restrict__ cnt, int* __restrict__ offs,
                             int* __restrict__ aux) {
    __shared__ int sh[256];
    int i = blockIdx.x * 256 + threadIdx.x;
    int v = (i < N_NODES) ? cnt[i] : 0;
    sh[threadIdx.x] = v;
    __syncthreads();
    for (int d = 1; d < 256; d <<= 1) {
        int t = (threadIdx.x >= d) ? sh[threadIdx.x - d] : 0;
        __syncthreads();
        sh[threadIdx.x] += t;
        __syncthreads();
    }
    if (i < N_NODES) offs[i] = sh[threadIdx.x] - v;   // exclusive
    if (threadIdx.x == 255) aux[blockIdx.x] = sh[255];
}

__global__ void scan2_kernel(int* __restrict__ aux) {
    __shared__ int sh[256];
    int t = threadIdx.x;
    int v = (t < SCAN_BLOCKS) ? aux[t] : 0;
    sh[t] = v;
    __syncthreads();
    for (int d = 1; d < 256; d <<= 1) {
        int u = (t >= d) ? sh[t - d] : 0;
        __syncthreads();
        sh[t] += u;
        __syncthreads();
    }
    if (t < SCAN_BLOCKS) aux[t] = sh[t] - v;          // exclusive
}

__global__ void scan3_kernel(int* __restrict__ offs, const int* __restrict__ aux) {
    int i = blockIdx.x * 256 + threadIdx.x;
    if (i < N_NODES) offs[i] += aux[blockIdx.x];
    if (i == 0) offs[N_NODES] = E_EDGES;
}

// ---------------------------------------------------------------- CSR: fill (reverse, reuses cnt as cursor)
__global__ void fill_kernel(const int* __restrict__ ei, const int* __restrict__ et,
                            const int* __restrict__ offs, int* __restrict__ cnt,
                            int* __restrict__ elist) {
    int e = blockIdx.x * blockDim.x + threadIdx.x;
    if (e >= E_EDGES) return;
    int src = ei[e];
    int dst = ei[E_EDGES + e];
    int r = et[e];
    int pos = offs[dst] + atomicSub(&cnt[dst], 1) - 1;
    elist[pos] = src | (r << 16);                      // src < 50000 < 2^16
}

// ---------------------------------------------------------------- gather aggregation: per-rel means
// 32 lanes per dst node (c = float4 column), 8 nodes per 256-thread block.
__global__ __launch_bounds__(256) void agg_kernel(const float* __restrict__ A_in,  // x rows at A+3*DH
                                                  const int* __restrict__ offs,
                                                  const int* __restrict__ elist,
                                                  float* __restrict__ A_out) {
    int t = threadIdx.x;
    int g = t >> 5, c = t & 31;
    int n = blockIdx.x * 8 + g;
    if (n >= N_NODES) return;
    int beg = offs[n], end = offs[n + 1];
    float a0x = 0, a0y = 0, a0z = 0, a0w = 0;
    float a1x = 0, a1y = 0, a1z = 0, a1w = 0;
    float a2x = 0, a2y = 0, a2z = 0, a2w = 0;
    int c0 = 0, c1 = 0, c2 = 0;
    for (int i = beg; i < end; ++i) {
        int pk = elist[i];                 // same addr across 32 lanes -> broadcast
        int src = pk & 0xFFFF;
        int rel = pk >> 16;
        const float4 v = *reinterpret_cast<const float4*>(
            A_in + (size_t)src * AST + 3 * DH + c * 4);
        if (rel == 0)      { a0x += v.x; a0y += v.y; a0z += v.z; a0w += v.w; c0++; }
        else if (rel == 1) { a1x += v.x; a1y += v.y; a1z += v.z; a1w += v.w; c1++; }
        else               { a2x += v.x; a2y += v.y; a2z += v.z; a2w += v.w; c2++; }
    }
    float i0 = c0 ? 1.f / c0 : 0.f;
    float i1 = c1 ? 1.f / c1 : 0.f;
    float i2 = c2 ? 1.f / c2 : 0.f;
    float4 o;
    float* base = A_out + (size_t)n * AST + c * 4;
    o.x = a0x * i0; o.y = a0y * i0; o.z = a0z * i0; o.w = a0w * i0;
    *reinterpret_cast<float4*>(base + 0 * DH) = o;
    o.x = a1x * i1; o.y = a1y * i1; o.z = a1z * i1; o.w = a1w * i1;
    *reinterpret_cast<float4*>(base + 1 * DH) = o;
    o.x = a2x * i2; o.y = a2y * i2; o.z = a2z * i2; o.w = a2w * i2;
    *reinterpret_cast<float4*>(base + 2 * DH) = o;
}

// ---------------------------------------------------------------- fused GEMM + BN(eval) + ReLU
// out[n,h] = relu( sc[h]*( sum_k A[n,k,:] @ Wk ) + shift[h] ), k=0..2 -> W[k], k=3 -> root
__global__ __launch_bounds__(256) void rgcn_gemm_bn_relu(
        const float* __restrict__ A, const float* __restrict__ W,
        const float* __restrict__ root, const float* __restrict__ bias,
        const float* __restrict__ g, const float* __restrict__ beta,
        const float* __restrict__ m, const float* __restrict__ v,
        float* __restrict__ out) {                     // out row stride = AST
    __shared__ float Ash[DH][36];
    const int n0 = blockIdx.x * 32;
    const int t = threadIdx.x;
    const int cg = t >> 3;
    const int ngp = t & 7;

    float acc00 = 0, acc01 = 0, acc02 = 0, acc03 = 0;
    float acc10 = 0, acc11 = 0, acc12 = 0, acc13 = 0;
    float acc20 = 0, acc21 = 0, acc22 = 0, acc23 = 0;
    float acc30 = 0, acc31 = 0, acc32 = 0, acc33 = 0;

    for (int k = 0; k < 4; ++k) {
        __syncthreads();
        {
            int i = t >> 3;
            int dq = (t & 7) * 16;
            int n = n0 + i;
            if (n < N_NODES) {
                const float4* srcp = reinterpret_cast<const float4*>(
                    A + ((size_t)n * 4 + k) * DH + dq);
                #pragma unroll
                for (int j = 0; j < 4; ++j) {
                    float4 val = srcp[j];
                    int d0 = dq + j * 4;
                    Ash[d0 + 0][i] = val.x;
                    Ash[d0 + 1][i] = val.y;
                    Ash[d0 + 2][i] = val.z;
                    Ash[d0 + 3][i] = val.w;
                }
            } else {
                #pragma unroll
                for (int j = 0; j < 4; ++j) {
                    int d0 = dq + j * 4;
                    Ash[d0 + 0][i] = 0.f; Ash[d0 + 1][i] = 0.f;
                    Ash[d0 + 2][i] = 0.f; Ash[d0 + 3][i] = 0.f;
                }
            }
        }
        __syncthreads();

        const float* Wk = (k < 3) ? (W + (size_t)k * DH * DH) : root;
        #pragma unroll 8
        for (int d = 0; d < DH; ++d) {
            const float4 a4 = *reinterpret_cast<const float4*>(&Ash[d][ngp * 4]);
            const float4 w4 = *reinterpret_cast<const float4*>(Wk + (size_t)d * DH + cg * 4);
            acc00 += a4.x * w4.x; acc01 += a4.x * w4.y; acc02 += a4.x * w4.z; acc03 += a4.x * w4.w;
            acc10 += a4.y * w4.x; acc11 += a4.y * w4.y; acc12 += a4.y * w4.z; acc13 += a4.y * w4.w;
            acc20 += a4.z * w4.x; acc21 += a4.z * w4.y; acc22 += a4.z * w4.z; acc23 += a4.z * w4.w;
            acc30 += a4.w * w4.x; acc31 += a4.w * w4.y; acc32 += a4.w * w4.z; acc33 += a4.w * w4.w;
        }
    }

    int hb = cg * 4;
    float sc0 = g[hb + 0] * rsqrtf(v[hb + 0] + EPSV);
    float sc1 = g[hb + 1] * rsqrtf(v[hb + 1] + EPSV);
    float sc2 = g[hb + 2] * rsqrtf(v[hb + 2] + EPSV);
    float sc3 = g[hb + 3] * rsqrtf(v[hb + 3] + EPSV);
    float sh0 = (bias[hb + 0] - m[hb + 0]) * sc0 + beta[hb + 0];
    float sh1 = (bias[hb + 1] - m[hb + 1]) * sc1 + beta[hb + 1];
    float sh2 = (bias[hb + 2] - m[hb + 2]) * sc2 + beta[hb + 2];
    float sh3 = (bias[hb + 3] - m[hb + 3]) * sc3 + beta[hb + 3];

    float accs[4][4] = {
        {acc00, acc01, acc02, acc03},
        {acc10, acc11, acc12, acc13},
        {acc20, acc21, acc22, acc23},
        {acc30, acc31, acc32, acc33}};
    #pragma unroll
    for (int i = 0; i < 4; ++i) {
        int n = n0 + ngp * 4 + i;
        if (n < N_NODES) {
            float4 o;
            o.x = fmaxf(accs[i][0] * sc0 + sh0, 0.f);
            o.y = fmaxf(accs[i][1] * sc1 + sh1, 0.f);
            o.z = fmaxf(accs[i][2] * sc2 + sh2, 0.f);
            o.w = fmaxf(accs[i][3] * sc3 + sh3, 0.f);
            *reinterpret_cast<float4*>(out + (size_t)n * AST + hb) = o;
        }
    }
}

// ---------------------------------------------------------------- global mean pool (sum part)
__global__ void pool_kernel(const float* __restrict__ h,      // rows at stride AST
                            const int* __restrict__ batch,
                            float* __restrict__ pool,
                            int* __restrict__ pcnt) {
    int tid = blockIdx.x * blockDim.x + threadIdx.x;
    int node = tid >> 5, c = tid & 31;
    if (node >= N_NODES) return;
    int b = batch[node];
    const float4 v = *reinterpret_cast<const float4*>(h + (size_t)node * AST + c * 4);
    float* p = pool + (size_t)b * DH + c * 4;
    atomicAdd(p + 0, v.x);
    atomicAdd(p + 1, v.y);
    atomicAdd(p + 2, v.z);
    atomicAdd(p + 3, v.w);
    if (c == 0) atomicAdd(&pcnt[b], 1);
}

// ---------------------------------------------------------------- classifier
__global__ void classify_kernel(const float* __restrict__ pool,
                                const int* __restrict__ pcnt,
                                const float* __restrict__ clsW,
                                const float* __restrict__ clsb,
                                float* __restrict__ out) {
    int tid = blockIdx.x * blockDim.x + threadIdx.x;
    if (tid >= BATCHES * NCLASS) return;
    int b = tid / NCLASS, c = tid % NCLASS;
    float cnt = (float)pcnt[b];
    float inv = cnt > 0.f ? 1.f / cnt : 1.f;
    const float* pr = pool + (size_t)b * DH;
    float s = 0.f;
    #pragma unroll 8
    for (int h = 0; h < DH; ++h) s += pr[h] * clsW[h * NCLASS + c];
    out[tid] = s * inv + clsb[c];
}

// ---------------------------------------------------------------- launch
extern "C" void kernel_launch(void* const* d_in, const int* in_sizes, int n_in,
                              void* d_out, int out_size, void* d_ws, size_t ws_size,
                              hipStream_t stream) {
    const int*   x_idx  = (const int*)d_in[0];
    const int*   eidx   = (const int*)d_in[1];
    const int*   etype  = (const int*)d_in[2];
    const int*   batch  = (const int*)d_in[3];
    const float* se     = (const float*)d_in[4];
    const float* ce     = (const float*)d_in[5];
    const float* pe     = (const float*)d_in[6];
    const float* W1     = (const float*)d_in[7];
    const float* root1  = (const float*)d_in[8];
    const float* b1     = (const float*)d_in[9];
    const float* g1     = (const float*)d_in[10];
    const float* beta1  = (const float*)d_in[11];
    const float* m1     = (const float*)d_in[12];
    const float* v1     = (const float*)d_in[13];
    const float* W2     = (const float*)d_in[14];
    const float* root2  = (const float*)d_in[15];
    const float* b2     = (const float*)d_in[16];
    const float* g2     = (const float*)d_in[17];
    const float* beta2  = (const float*)d_in[18];
    const float* m2     = (const float*)d_in[19];
    const float* v2     = (const float*)d_in[20];
    const float* clsW   = (const float*)d_in[21];
    const float* clsb   = (const float*)d_in[22];
    float* out = (float*)d_out;

    // workspace layout
    char* ws = (char*)d_ws;
    const size_t A_bytes     = (size_t)N_NODES * AST * 4;    // 102,400,000
    const size_t elist_bytes = (size_t)E_EDGES * 4;          //   3,200,000
    const size_t offs_bytes  = ((size_t)N_NODES + 1) * 4;    //     200,004
    const size_t offs_pad    = 200064;
    float* A     = (float*)(ws);
    int*   elist = (int*)(ws + A_bytes);
    int*   offs  = (int*)(ws + A_bytes + elist_bytes);
    int*   cnt   = (int*)(ws + A_bytes + elist_bytes + offs_pad);          // 200,000 B
    int*   aux   = (int*)(ws + A_bytes + elist_bytes + offs_pad + 200000); //   1,024 B
    // pool/pcnt alias the cnt region (cnt dead after fill_kernel)
    float* pool  = (float*)cnt;
    int*   pcnt  = (int*)((char*)cnt + (size_t)BATCHES * DH * 4);

    const int TB = 256;

    hipMemsetAsync(cnt, 0, (size_t)N_NODES * 4, stream);

    // x embeddings -> A[n][3]
    build_x_kernel<<<(N_NODES * 32 + TB - 1) / TB, TB, 0, stream>>>(x_idx, se, ce, pe, A);

    // CSR by dst (shared by both layers)
    count_dst_kernel<<<(E_EDGES + TB - 1) / TB, TB, 0, stream>>>(eidx, cnt);
    scan1_kernel<<<SCAN_BLOCKS, 256, 0, stream>>>(cnt, offs, aux);
    scan2_kernel<<<1, 256, 0, stream>>>(aux);
    scan3_kernel<<<SCAN_BLOCKS, 256, 0, stream>>>(offs, aux);
    fill_kernel<<<(E_EDGES + TB - 1) / TB, TB, 0, stream>>>(eidx, etype, offs, cnt, elist);

    // ----- layer 1
    agg_kernel<<<(N_NODES + 7) / 8, 256, 0, stream>>>(A, offs, elist, A);
    rgcn_gemm_bn_relu<<<(N_NODES + 31) / 32, TB, 0, stream>>>(
        A, W1, root1, b1, g1, beta1, m1, v1, A + 3 * DH);   // h1 -> A[n][3]

    // ----- layer 2
    agg_kernel<<<(N_NODES + 7) / 8, 256, 0, stream>>>(A, offs, elist, A);
    rgcn_gemm_bn_relu<<<(N_NODES + 31) / 32, TB, 0, stream>>>(
        A, W2, root2, b2, g2, beta2, m2, v2, A + 3 * DH);   // h2 -> A[n][3]

    // ----- global mean pool + classifier
    hipMemsetAsync(pool, 0, (size_t)BATCHES * DH * 4 + BATCHES * 4, stream);
    pool_kernel<<<(N_NODES * 32 + TB - 1) / TB, TB, 0, stream>>>(A + 3 * DH, batch, pool, pcnt);
    classify_kernel<<<(BATCHES * NCLASS + TB - 1) / TB, TB, 0, stream>>>(
        pool, pcnt, clsW, clsb, out);
}

// Round 3
// 524.132 us; speedup vs baseline: 6.1334x; 1.2905x over previous
//
#include <hip/hip_runtime.h>

#define N_NODES 50000
#define E_EDGES 800000
#define R_REL 3
#define DH 128
#define AST (4 * DH)          // A row stride: [mean_r0 | mean_r1 | mean_r2 | x/h]
#define BATCHES 256
#define NCLASS 10
#define EPSV 1e-5f
#define SCAN_BLOCKS ((N_NODES + 255) / 256)   // 196

// ---------------------------------------------------------------- build x into A[n][3]
__global__ void build_x_kernel(const int* __restrict__ xi,
                               const float* __restrict__ se,
                               const float* __restrict__ ce,
                               const float* __restrict__ pe,
                               float* __restrict__ A) {
    int tid = blockIdx.x * blockDim.x + threadIdx.x;   // N*32 threads
    int node = tid >> 5, c = tid & 31;
    if (node >= N_NODES) return;
    int i0 = xi[node * 3 + 0];
    int i1 = xi[node * 3 + 1];
    int i2 = xi[node * 3 + 2];
    i2 = i2 < 0 ? 0 : (i2 > 24 ? 24 : i2);
    const float4 a = *reinterpret_cast<const float4*>(se + (size_t)i0 * DH + c * 4);
    const float4 b = *reinterpret_cast<const float4*>(ce + (size_t)i1 * DH + c * 4);
    const float4 p = *reinterpret_cast<const float4*>(pe + (size_t)i2 * DH + c * 4);
    float4 o;
    o.x = a.x + b.x + p.x; o.y = a.y + b.y + p.y;
    o.z = a.z + b.z + p.z; o.w = a.w + b.w + p.w;
    *reinterpret_cast<float4*>(A + (size_t)node * AST + 3 * DH + c * 4) = o;
}

// ---------------------------------------------------------------- CSR: per-dst degree
__global__ void count_dst_kernel(const int* __restrict__ ei, int* __restrict__ cnt) {
    int e = blockIdx.x * blockDim.x + threadIdx.x;
    if (e >= E_EDGES) return;
    atomicAdd(&cnt[ei[E_EDGES + e]], 1);
}

// ---------------------------------------------------------------- CSR: hierarchical exclusive scan
__global__ void scan1_kernel(const int* __restrict__ cnt, int* __restrict__ offs,
                             int* __restrict__ aux) {
    __shared__ int sh[256];
    int i = blockIdx.x * 256 + threadIdx.x;
    int v = (i < N_NODES) ? cnt[i] : 0;
    sh[threadIdx.x] = v;
    __syncthreads();
    for (int d = 1; d < 256; d <<= 1) {
        int t = (threadIdx.x >= d) ? sh[threadIdx.x - d] : 0;
        __syncthreads();
        sh[threadIdx.x] += t;
        __syncthreads();
    }
    if (i < N_NODES) offs[i] = sh[threadIdx.x] - v;   // exclusive
    if (threadIdx.x == 255) aux[blockIdx.x] = sh[255];
}

__global__ void scan2_kernel(int* __restrict__ aux) {
    __shared__ int sh[256];
    int t = threadIdx.x;
    int v = (t < SCAN_BLOCKS) ? aux[t] : 0;
    sh[t] = v;
    __syncthreads();
    for (int d = 1; d < 256; d <<= 1) {
        int u = (t >= d) ? sh[t - d] : 0;
        __syncthreads();
        sh[t] += u;
        __syncthreads();
    }
    if (t < SCAN_BLOCKS) aux[t] = sh[t] - v;          // exclusive
}

__global__ void scan3_kernel(int* __restrict__ offs, const int* __restrict__ aux) {
    int i = blockIdx.x * 256 + threadIdx.x;
    if (i < N_NODES) offs[i] += aux[blockIdx.x];
    if (i == 0) offs[N_NODES] = E_EDGES;
}

// ---------------------------------------------------------------- CSR: fill (reverse, reuses cnt as cursor)
__global__ void fill_kernel(const int* __restrict__ ei, const int* __restrict__ et,
                            const int* __restrict__ offs, int* __restrict__ cnt,
                            int* __restrict__ elist) {
    int e = blockIdx.x * blockDim.x + threadIdx.x;
    if (e >= E_EDGES) return;
    int src = ei[e];
    int dst = ei[E_EDGES + e];
    int r = et[e];
    int pos = offs[dst] + atomicSub(&cnt[dst], 1) - 1;
    elist[pos] = src | (r << 16);                      // src < 50000 < 2^16
}

// ---------------------------------------------------------------- batch segment bounds (batch is sorted)
__global__ void bounds_kernel(const int* __restrict__ batch, int* __restrict__ bstart) {
    int b = blockIdx.x * blockDim.x + threadIdx.x;
    if (b > BATCHES) return;
    int lo = 0, hi = N_NODES;                          // first i with batch[i] >= b
    while (lo < hi) {
        int mid = (lo + hi) >> 1;
        if (batch[mid] < b) lo = mid + 1; else hi = mid;
    }
    bstart[b] = lo;
}

// ---------------------------------------------------------------- gather aggregation: per-rel means
// 32 lanes per dst node (c = float4 column), 8 nodes per 256-thread block.
__global__ __launch_bounds__(256) void agg_kernel(const float* __restrict__ A_in,  // x rows at A+3*DH
                                                  const int* __restrict__ offs,
                                                  const int* __restrict__ elist,
                                                  float* __restrict__ A_out) {
    int t = threadIdx.x;
    int g = t >> 5, c = t & 31;
    int n = blockIdx.x * 8 + g;
    if (n >= N_NODES) return;
    int beg = offs[n], end = offs[n + 1];
    float a0x = 0, a0y = 0, a0z = 0, a0w = 0;
    float a1x = 0, a1y = 0, a1z = 0, a1w = 0;
    float a2x = 0, a2y = 0, a2z = 0, a2w = 0;
    int c0 = 0, c1 = 0, c2 = 0;
    for (int i = beg; i < end; ++i) {
        int pk = elist[i];                 // same addr across 32 lanes -> broadcast
        int src = pk & 0xFFFF;
        int rel = pk >> 16;
        const float4 v = *reinterpret_cast<const float4*>(
            A_in + (size_t)src * AST + 3 * DH + c * 4);
        if (rel == 0)      { a0x += v.x; a0y += v.y; a0z += v.z; a0w += v.w; c0++; }
        else if (rel == 1) { a1x += v.x; a1y += v.y; a1z += v.z; a1w += v.w; c1++; }
        else               { a2x += v.x; a2y += v.y; a2z += v.z; a2w += v.w; c2++; }
    }
    float i0 = c0 ? 1.f / c0 : 0.f;
    float i1 = c1 ? 1.f / c1 : 0.f;
    float i2 = c2 ? 1.f / c2 : 0.f;
    float4 o;
    float* base = A_out + (size_t)n * AST + c * 4;
    o.x = a0x * i0; o.y = a0y * i0; o.z = a0z * i0; o.w = a0w * i0;
    *reinterpret_cast<float4*>(base + 0 * DH) = o;
    o.x = a1x * i1; o.y = a1y * i1; o.z = a1z * i1; o.w = a1w * i1;
    *reinterpret_cast<float4*>(base + 1 * DH) = o;
    o.x = a2x * i2; o.y = a2y * i2; o.z = a2z * i2; o.w = a2w * i2;
    *reinterpret_cast<float4*>(base + 2 * DH) = o;
}

// ---------------------------------------------------------------- fused GEMM + BN(eval) + ReLU
// out[n,h] = relu( sc[h]*( sum_k A[n,k,:] @ Wk ) + shift[h] ), k=0..2 -> W[k], k=3 -> root
__global__ __launch_bounds__(256) void rgcn_gemm_bn_relu(
        const float* __restrict__ A, const float* __restrict__ W,
        const float* __restrict__ root, const float* __restrict__ bias,
        const float* __restrict__ g, const float* __restrict__ beta,
        const float* __restrict__ m, const float* __restrict__ v,
        float* __restrict__ out) {                     // out row stride = AST
    __shared__ float Ash[DH][36];
    const int n0 = blockIdx.x * 32;
    const int t = threadIdx.x;
    const int cg = t >> 3;
    const int ngp = t & 7;

    float acc00 = 0, acc01 = 0, acc02 = 0, acc03 = 0;
    float acc10 = 0, acc11 = 0, acc12 = 0, acc13 = 0;
    float acc20 = 0, acc21 = 0, acc22 = 0, acc23 = 0;
    float acc30 = 0, acc31 = 0, acc32 = 0, acc33 = 0;

    for (int k = 0; k < 4; ++k) {
        __syncthreads();
        {
            int i = t >> 3;
            int dq = (t & 7) * 16;
            int n = n0 + i;
            if (n < N_NODES) {
                const float4* srcp = reinterpret_cast<const float4*>(
                    A + ((size_t)n * 4 + k) * DH + dq);
                #pragma unroll
                for (int j = 0; j < 4; ++j) {
                    float4 val = srcp[j];
                    int d0 = dq + j * 4;
                    Ash[d0 + 0][i] = val.x;
                    Ash[d0 + 1][i] = val.y;
                    Ash[d0 + 2][i] = val.z;
                    Ash[d0 + 3][i] = val.w;
                }
            } else {
                #pragma unroll
                for (int j = 0; j < 4; ++j) {
                    int d0 = dq + j * 4;
                    Ash[d0 + 0][i] = 0.f; Ash[d0 + 1][i] = 0.f;
                    Ash[d0 + 2][i] = 0.f; Ash[d0 + 3][i] = 0.f;
                }
            }
        }
        __syncthreads();

        const float* Wk = (k < 3) ? (W + (size_t)k * DH * DH) : root;
        #pragma unroll 8
        for (int d = 0; d < DH; ++d) {
            const float4 a4 = *reinterpret_cast<const float4*>(&Ash[d][ngp * 4]);
            const float4 w4 = *reinterpret_cast<const float4*>(Wk + (size_t)d * DH + cg * 4);
            acc00 += a4.x * w4.x; acc01 += a4.x * w4.y; acc02 += a4.x * w4.z; acc03 += a4.x * w4.w;
            acc10 += a4.y * w4.x; acc11 += a4.y * w4.y; acc12 += a4.y * w4.z; acc13 += a4.y * w4.w;
            acc20 += a4.z * w4.x; acc21 += a4.z * w4.y; acc22 += a4.z * w4.z; acc23 += a4.z * w4.w;
            acc30 += a4.w * w4.x; acc31 += a4.w * w4.y; acc32 += a4.w * w4.z; acc33 += a4.w * w4.w;
        }
    }

    int hb = cg * 4;
    float sc0 = g[hb + 0] * rsqrtf(v[hb + 0] + EPSV);
    float sc1 = g[hb + 1] * rsqrtf(v[hb + 1] + EPSV);
    float sc2 = g[hb + 2] * rsqrtf(v[hb + 2] + EPSV);
    float sc3 = g[hb + 3] * rsqrtf(v[hb + 3] + EPSV);
    float sh0 = (bias[hb + 0] - m[hb + 0]) * sc0 + beta[hb + 0];
    float sh1 = (bias[hb + 1] - m[hb + 1]) * sc1 + beta[hb + 1];
    float sh2 = (bias[hb + 2] - m[hb + 2]) * sc2 + beta[hb + 2];
    float sh3 = (bias[hb + 3] - m[hb + 3]) * sc3 + beta[hb + 3];

    float accs[4][4] = {
        {acc00, acc01, acc02, acc03},
        {acc10, acc11, acc12, acc13},
        {acc20, acc21, acc22, acc23},
        {acc30, acc31, acc32, acc33}};
    #pragma unroll
    for (int i = 0; i < 4; ++i) {
        int n = n0 + ngp * 4 + i;
        if (n < N_NODES) {
            float4 o;
            o.x = fmaxf(accs[i][0] * sc0 + sh0, 0.f);
            o.y = fmaxf(accs[i][1] * sc1 + sh1, 0.f);
            o.z = fmaxf(accs[i][2] * sc2 + sh2, 0.f);
            o.w = fmaxf(accs[i][3] * sc3 + sh3, 0.f);
            *reinterpret_cast<float4*>(out + (size_t)n * AST + hb) = o;
        }
    }
}

// ---------------------------------------------------------------- fused global-mean-pool + classifier
// one block per batch segment (batch sorted): coalesced segment sum, no atomics
__global__ __launch_bounds__(256) void pool_cls_kernel(
        const float* __restrict__ h,               // rows at stride AST
        const int* __restrict__ bstart,
        const float* __restrict__ clsW,
        const float* __restrict__ clsb,
        float* __restrict__ out) {
    __shared__ float hsh[DH];
    int b = blockIdx.x;
    int t = threadIdx.x;
    int c = t & 127;          // column
    int half = t >> 7;        // 0/1: rows strided by 2
    int beg = bstart[b], end = bstart[b + 1];
    float s = 0.f;
    for (int n = beg + half; n < end; n += 2)
        s += h[(size_t)n * AST + c];
    // combine the two halves
    if (half == 1) hsh[c] = s;
    __syncthreads();
    if (half == 0) {
        float cnt = (float)(end - beg);
        float inv = cnt > 0.f ? 1.f / cnt : 1.f;
        hsh[c] = (s + hsh[c]) * inv;      // mean
    }
    __syncthreads();
    if (t < NCLASS) {
        float acc = clsb[t];
        #pragma unroll 16
        for (int d = 0; d < DH; ++d)
            acc += hsh[d] * clsW[d * NCLASS + t];
        out[b * NCLASS + t] = acc;
    }
}

// ---------------------------------------------------------------- launch
extern "C" void kernel_launch(void* const* d_in, const int* in_sizes, int n_in,
                              void* d_out, int out_size, void* d_ws, size_t ws_size,
                              hipStream_t stream) {
    const int*   x_idx  = (const int*)d_in[0];
    const int*   eidx   = (const int*)d_in[1];
    const int*   etype  = (const int*)d_in[2];
    const int*   batch  = (const int*)d_in[3];
    const float* se     = (const float*)d_in[4];
    const float* ce     = (const float*)d_in[5];
    const float* pe     = (const float*)d_in[6];
    const float* W1     = (const float*)d_in[7];
    const float* root1  = (const float*)d_in[8];
    const float* b1     = (const float*)d_in[9];
    const float* g1     = (const float*)d_in[10];
    const float* beta1  = (const float*)d_in[11];
    const float* m1     = (const float*)d_in[12];
    const float* v1     = (const float*)d_in[13];
    const float* W2     = (const float*)d_in[14];
    const float* root2  = (const float*)d_in[15];
    const float* b2     = (const float*)d_in[16];
    const float* g2     = (const float*)d_in[17];
    const float* beta2  = (const float*)d_in[18];
    const float* m2     = (const float*)d_in[19];
    const float* v2     = (const float*)d_in[20];
    const float* clsW   = (const float*)d_in[21];
    const float* clsb   = (const float*)d_in[22];
    float* out = (float*)d_out;

    // workspace layout
    char* ws = (char*)d_ws;
    const size_t A_bytes     = (size_t)N_NODES * AST * 4;    // 102,400,000
    const size_t elist_bytes = (size_t)E_EDGES * 4;          //   3,200,000
    const size_t offs_pad    = 200064;
    float* A      = (float*)(ws);
    int*   elist  = (int*)(ws + A_bytes);
    int*   offs   = (int*)(ws + A_bytes + elist_bytes);
    int*   cnt    = (int*)(ws + A_bytes + elist_bytes + offs_pad);          // 200,000 B
    int*   aux    = (int*)(ws + A_bytes + elist_bytes + offs_pad + 200000); //   1,024 B
    int*   bstart = (int*)(ws + A_bytes + elist_bytes + offs_pad + 201024); //   1,028 B

    const int TB = 256;

    hipMemsetAsync(cnt, 0, (size_t)N_NODES * 4, stream);

    // x embeddings -> A[n][3]
    build_x_kernel<<<(N_NODES * 32 + TB - 1) / TB, TB, 0, stream>>>(x_idx, se, ce, pe, A);

    // CSR by dst (shared by both layers) + batch bounds
    count_dst_kernel<<<(E_EDGES + TB - 1) / TB, TB, 0, stream>>>(eidx, cnt);
    scan1_kernel<<<SCAN_BLOCKS, 256, 0, stream>>>(cnt, offs, aux);
    scan2_kernel<<<1, 256, 0, stream>>>(aux);
    scan3_kernel<<<SCAN_BLOCKS, 256, 0, stream>>>(offs, aux);
    fill_kernel<<<(E_EDGES + TB - 1) / TB, TB, 0, stream>>>(eidx, etype, offs, cnt, elist);
    bounds_kernel<<<2, 256, 0, stream>>>(batch, bstart);

    // ----- layer 1
    agg_kernel<<<(N_NODES + 7) / 8, 256, 0, stream>>>(A, offs, elist, A);
    rgcn_gemm_bn_relu<<<(N_NODES + 31) / 32, TB, 0, stream>>>(
        A, W1, root1, b1, g1, beta1, m1, v1, A + 3 * DH);   // h1 -> A[n][3]

    // ----- layer 2
    agg_kernel<<<(N_NODES + 7) / 8, 256, 0, stream>>>(A, offs, elist, A);
    rgcn_gemm_bn_relu<<<(N_NODES + 31) / 32, TB, 0, stream>>>(
        A, W2, root2, b2, g2, beta2, m2, v2, A + 3 * DH);   // h2 -> A[n][3]

    // ----- fused global mean pool + classifier (batch sorted -> segment sums)
    pool_cls_kernel<<<BATCHES, 256, 0, stream>>>(A + 3 * DH, bstart, clsW, clsb, out);
}

// Round 4
// 303.182 us; speedup vs baseline: 10.6032x; 1.7288x over previous
//
#include <hip/hip_runtime.h>

#define N_NODES 50000
#define E_EDGES 800000
#define R_REL 3
#define DH 128
#define KDIM 512              // A row: [mean_r0 | mean_r1 | mean_r2 | x/h] in bf16
#define BATCHES 256
#define NCLASS 10
#define EPSV 1e-5f
#define SCAN_BLOCKS ((N_NODES + 255) / 256)   // 196

typedef __attribute__((ext_vector_type(8))) short short8v;
typedef __attribute__((ext_vector_type(4))) float float4v;
typedef unsigned short ushort_t;

__device__ __forceinline__ ushort_t f2bf(float f) {
    union { float f; unsigned u; } x; x.f = f;
    unsigned r = x.u + 0x7FFFu + ((x.u >> 16) & 1u);
    return (ushort_t)(r >> 16);
}
__device__ __forceinline__ float bf2f(ushort_t h) {
    union { unsigned u; float f; } x; x.u = ((unsigned)h) << 16;
    return x.f;
}

// ---------------------------------------------------------------- build x (bf16) into A[n][3*128..]
__global__ void build_x_kernel(const int* __restrict__ xi,
                               const float* __restrict__ se,
                               const float* __restrict__ ce,
                               const float* __restrict__ pe,
                               ushort_t* __restrict__ A) {
    int tid = blockIdx.x * blockDim.x + threadIdx.x;   // N*16 threads
    int node = tid >> 4, c = tid & 15;                 // c -> cols c*8..c*8+7
    if (node >= N_NODES) return;
    int i0 = xi[node * 3 + 0];
    int i1 = xi[node * 3 + 1];
    int i2 = xi[node * 3 + 2];
    i2 = i2 < 0 ? 0 : (i2 > 24 ? 24 : i2);
    const float4* sa = reinterpret_cast<const float4*>(se + (size_t)i0 * DH + c * 8);
    const float4* sb = reinterpret_cast<const float4*>(ce + (size_t)i1 * DH + c * 8);
    const float4* sp = reinterpret_cast<const float4*>(pe + (size_t)i2 * DH + c * 8);
    short8v o;
    #pragma unroll
    for (int q = 0; q < 2; ++q) {
        float4 a = sa[q], b = sb[q], p = sp[q];
        o[q * 4 + 0] = (short)f2bf(a.x + b.x + p.x);
        o[q * 4 + 1] = (short)f2bf(a.y + b.y + p.y);
        o[q * 4 + 2] = (short)f2bf(a.z + b.z + p.z);
        o[q * 4 + 3] = (short)f2bf(a.w + b.w + p.w);
    }
    *reinterpret_cast<short8v*>(A + (size_t)node * KDIM + 3 * DH + c * 8) = o;
}

// ---------------------------------------------------------------- CSR: per-dst degree
__global__ void count_dst_kernel(const int* __restrict__ ei, int* __restrict__ cnt) {
    int e = blockIdx.x * blockDim.x + threadIdx.x;
    if (e >= E_EDGES) return;
    atomicAdd(&cnt[ei[E_EDGES + e]], 1);
}

// ---------------------------------------------------------------- CSR: hierarchical exclusive scan
__global__ void scan1_kernel(const int* __restrict__ cnt, int* __restrict__ offs,
                             int* __restrict__ aux) {
    __shared__ int sh[256];
    int i = blockIdx.x * 256 + threadIdx.x;
    int v = (i < N_NODES) ? cnt[i] : 0;
    sh[threadIdx.x] = v;
    __syncthreads();
    for (int d = 1; d < 256; d <<= 1) {
        int t = (threadIdx.x >= d) ? sh[threadIdx.x - d] : 0;
        __syncthreads();
        sh[threadIdx.x] += t;
        __syncthreads();
    }
    if (i < N_NODES) offs[i] = sh[threadIdx.x] - v;   // exclusive
    if (threadIdx.x == 255) aux[blockIdx.x] = sh[255];
}

__global__ void scan2_kernel(int* __restrict__ aux) {
    __shared__ int sh[256];
    int t = threadIdx.x;
    int v = (t < SCAN_BLOCKS) ? aux[t] : 0;
    sh[t] = v;
    __syncthreads();
    for (int d = 1; d < 256; d <<= 1) {
        int u = (t >= d) ? sh[t - d] : 0;
        __syncthreads();
        sh[t] += u;
        __syncthreads();
    }
    if (t < SCAN_BLOCKS) aux[t] = sh[t] - v;          // exclusive
}

__global__ void scan3_kernel(int* __restrict__ offs, const int* __restrict__ aux) {
    int i = blockIdx.x * 256 + threadIdx.x;
    if (i < N_NODES) offs[i] += aux[blockIdx.x];
    if (i == 0) offs[N_NODES] = E_EDGES;
}

// ---------------------------------------------------------------- CSR: fill (reverse, reuses cnt as cursor)
__global__ void fill_kernel(const int* __restrict__ ei, const int* __restrict__ et,
                            const int* __restrict__ offs, int* __restrict__ cnt,
                            int* __restrict__ elist) {
    int e = blockIdx.x * blockDim.x + threadIdx.x;
    if (e >= E_EDGES) return;
    int src = ei[e];
    int dst = ei[E_EDGES + e];
    int r = et[e];
    int pos = offs[dst] + atomicSub(&cnt[dst], 1) - 1;
    elist[pos] = src | (r << 16);                      // src < 50000 < 2^16
}

// ---------------------------------------------------------------- batch segment bounds (batch is sorted)
__global__ void bounds_kernel(const int* __restrict__ batch, int* __restrict__ bstart) {
    int b = blockIdx.x * blockDim.x + threadIdx.x;
    if (b > BATCHES) return;
    int lo = 0, hi = N_NODES;
    while (lo < hi) {
        int mid = (lo + hi) >> 1;
        if (batch[mid] < b) lo = mid + 1; else hi = mid;
    }
    bstart[b] = lo;
}

// ---------------------------------------------------------------- weight pre-pack into MFMA B-frag order (bf16)
// Wfrag[ks][nt][lane][8]: element j = Wcat[k = ks*32 + (lane>>4)*8 + j][col = nt*16 + (lane&15)]
// Wcat rows: k<384 -> W[k/128][k%128][:], else root[k-384][:]
__global__ void prepack_w_kernel(const float* __restrict__ W1, const float* __restrict__ root1,
                                 const float* __restrict__ W2, const float* __restrict__ root2,
                                 ushort_t* __restrict__ Wf1, ushort_t* __restrict__ Wf2) {
    int tid = blockIdx.x * blockDim.x + threadIdx.x;   // 2*16*8*64 = 16384
    if (tid >= 16384) return;
    int L = tid >> 13;
    int rem = tid & 8191;
    int ks = rem >> 9;
    int nt = (rem >> 6) & 7;
    int l = rem & 63;
    const float* W = L ? W2 : W1;
    const float* root = L ? root2 : root1;
    ushort_t* dst = (L ? Wf2 : Wf1) + (size_t)rem * 8;
    int col = nt * 16 + (l & 15);
    int kb = ks * 32 + (l >> 4) * 8;
    short8v o;
    #pragma unroll
    for (int j = 0; j < 8; ++j) {
        int k = kb + j;
        float w = (k < 384) ? W[(size_t)k * DH + col] : root[(size_t)(k - 384) * DH + col];
        o[j] = (short)f2bf(w);
    }
    *reinterpret_cast<short8v*>(dst) = o;
}

// ---------------------------------------------------------------- BN(eval) constant prep
__global__ void bn_prep_kernel(const float* __restrict__ b1, const float* __restrict__ g1,
                               const float* __restrict__ be1, const float* __restrict__ m1,
                               const float* __restrict__ v1,
                               const float* __restrict__ b2, const float* __restrict__ g2,
                               const float* __restrict__ be2, const float* __restrict__ m2,
                               const float* __restrict__ v2,
                               float* __restrict__ sc1, float* __restrict__ sh1,
                               float* __restrict__ sc2, float* __restrict__ sh2) {
    int t = threadIdx.x;
    if (t < DH) {
        float s = g1[t] * rsqrtf(v1[t] + EPSV);
        sc1[t] = s;
        sh1[t] = (b1[t] - m1[t]) * s + be1[t];
    } else if (t < 2 * DH) {
        int c = t - DH;
        float s = g2[c] * rsqrtf(v2[c] + EPSV);
        sc2[c] = s;
        sh2[c] = (b2[c] - m2[c]) * s + be2[c];
    }
}

// ---------------------------------------------------------------- gather aggregation (bf16): per-rel means
// 16 lanes per dst node (lane c -> cols c*8..+8), 16 nodes per 256-thread block.
__global__ __launch_bounds__(256) void agg_kernel(const ushort_t* __restrict__ A_in,
                                                  const int* __restrict__ offs,
                                                  const int* __restrict__ elist,
                                                  ushort_t* __restrict__ A_out) {
    int t = threadIdx.x;
    int g = t >> 4, c = t & 15;
    int n = blockIdx.x * 16 + g;
    if (n >= N_NODES) return;
    int beg = offs[n], end = offs[n + 1];
    float a0[8] = {0}, a1[8] = {0}, a2[8] = {0};
    int c0 = 0, c1 = 0, c2 = 0;

    int i = beg;
    short8v vc; int relc = 0;
    if (i < end) {
        int pk = elist[i];
        relc = pk >> 16;
        vc = *reinterpret_cast<const short8v*>(A_in + (size_t)(pk & 0xFFFF) * KDIM + 3 * DH + c * 8);
    }
    while (i < end) {
        int inext = i + 1;
        short8v vn; int reln = 0;
        if (inext < end) {
            int pk = elist[inext];
            reln = pk >> 16;
            vn = *reinterpret_cast<const short8v*>(A_in + (size_t)(pk & 0xFFFF) * KDIM + 3 * DH + c * 8);
        }
        float f[8];
        #pragma unroll
        for (int j = 0; j < 8; ++j) f[j] = bf2f((ushort_t)vc[j]);
        if (relc == 0) {
            #pragma unroll
            for (int j = 0; j < 8; ++j) a0[j] += f[j];
            c0++;
        } else if (relc == 1) {
            #pragma unroll
            for (int j = 0; j < 8; ++j) a1[j] += f[j];
            c1++;
        } else {
            #pragma unroll
            for (int j = 0; j < 8; ++j) a2[j] += f[j];
            c2++;
        }
        vc = vn; relc = reln; i = inext;
    }

    float i0 = c0 ? 1.f / c0 : 0.f;
    float i1 = c1 ? 1.f / c1 : 0.f;
    float i2 = c2 ? 1.f / c2 : 0.f;
    ushort_t* base = A_out + (size_t)n * KDIM + c * 8;
    short8v o;
    #pragma unroll
    for (int j = 0; j < 8; ++j) o[j] = (short)f2bf(a0[j] * i0);
    *reinterpret_cast<short8v*>(base + 0 * DH) = o;
    #pragma unroll
    for (int j = 0; j < 8; ++j) o[j] = (short)f2bf(a1[j] * i1);
    *reinterpret_cast<short8v*>(base + 1 * DH) = o;
    #pragma unroll
    for (int j = 0; j < 8; ++j) o[j] = (short)f2bf(a2[j] * i2);
    *reinterpret_cast<short8v*>(base + 2 * DH) = o;
}

// ---------------------------------------------------------------- MFMA GEMM + BN + ReLU
// C[50000x128] = A[50000x512](bf16) @ Wcat[512x128](bf16, pre-packed frags), f32 accum.
// Block: 256 thr = 4 waves; wave w -> rows blk*64 + w*16; 8 col-tiles of 16; 16 K-steps of 32.
__global__ __launch_bounds__(256) void gemm_mfma_kernel(const ushort_t* __restrict__ A,
                                                        const ushort_t* __restrict__ Wf,
                                                        const float* __restrict__ sc,
                                                        const float* __restrict__ sh,
                                                        ushort_t* __restrict__ Aout) {
    int w = threadIdx.x >> 6, l = threadIdx.x & 63;
    int base = blockIdx.x * 64 + w * 16;
    int arow = base + (l & 15);
    if (arow >= N_NODES) arow = N_NODES - 1;           // clamp loads; stores guarded
    const short8v* ap = reinterpret_cast<const short8v*>(A + (size_t)arow * KDIM + (l >> 4) * 8);
    const short8v* wf = reinterpret_cast<const short8v*>(Wf) + l;

    float4v acc[8];
    #pragma unroll
    for (int nt = 0; nt < 8; ++nt) acc[nt] = (float4v){0.f, 0.f, 0.f, 0.f};

    #pragma unroll 4
    for (int ks = 0; ks < 16; ++ks) {
        short8v a = ap[ks * 4];                        // k offset ks*32 shorts
        const short8v* bp = wf + ks * 512;             // [ks][nt][lane]
        #pragma unroll
        for (int nt = 0; nt < 8; ++nt) {
            short8v b = bp[nt * 64];
            acc[nt] = __builtin_amdgcn_mfma_f32_16x16x32_bf16(a, b, acc[nt], 0, 0, 0);
        }
    }

    int colb = l & 15;
    int rowq = (l >> 4) * 4;
    #pragma unroll
    for (int nt = 0; nt < 8; ++nt) {
        int col = nt * 16 + colb;
        float scv = sc[col], shv = sh[col];
        #pragma unroll
        for (int r = 0; r < 4; ++r) {
            int row = base + rowq + r;
            if (row < N_NODES) {
                float val = fmaxf(acc[nt][r] * scv + shv, 0.f);
                Aout[(size_t)row * KDIM + 3 * DH + col] = f2bf(val);
            }
        }
    }
}

// ---------------------------------------------------------------- fused global-mean-pool + classifier
__global__ __launch_bounds__(256) void pool_cls_kernel(
        const ushort_t* __restrict__ h,             // rows at stride KDIM, offset 3*DH applied by caller
        const int* __restrict__ bstart,
        const float* __restrict__ clsW,
        const float* __restrict__ clsb,
        float* __restrict__ out) {
    __shared__ float hsh[DH];
    int b = blockIdx.x;
    int t = threadIdx.x;
    int c = t & 127;
    int half = t >> 7;
    int beg = bstart[b], end = bstart[b + 1];
    float s = 0.f;
    for (int n = beg + half; n < end; n += 2)
        s += bf2f(h[(size_t)n * KDIM + c]);
    if (half == 1) hsh[c] = s;
    __syncthreads();
    if (half == 0) {
        float cnt = (float)(end - beg);
        float inv = cnt > 0.f ? 1.f / cnt : 1.f;
        hsh[c] = (s + hsh[c]) * inv;
    }
    __syncthreads();
    if (t < NCLASS) {
        float acc = clsb[t];
        #pragma unroll 16
        for (int d = 0; d < DH; ++d)
            acc += hsh[d] * clsW[d * NCLASS + t];
        out[b * NCLASS + t] = acc;
    }
}

// ---------------------------------------------------------------- launch
extern "C" void kernel_launch(void* const* d_in, const int* in_sizes, int n_in,
                              void* d_out, int out_size, void* d_ws, size_t ws_size,
                              hipStream_t stream) {
    const int*   x_idx  = (const int*)d_in[0];
    const int*   eidx   = (const int*)d_in[1];
    const int*   etype  = (const int*)d_in[2];
    const int*   batch  = (const int*)d_in[3];
    const float* se     = (const float*)d_in[4];
    const float* ce     = (const float*)d_in[5];
    const float* pe     = (const float*)d_in[6];
    const float* W1     = (const float*)d_in[7];
    const float* root1  = (const float*)d_in[8];
    const float* b1     = (const float*)d_in[9];
    const float* g1     = (const float*)d_in[10];
    const float* beta1  = (const float*)d_in[11];
    const float* m1     = (const float*)d_in[12];
    const float* v1     = (const float*)d_in[13];
    const float* W2     = (const float*)d_in[14];
    const float* root2  = (const float*)d_in[15];
    const float* b2     = (const float*)d_in[16];
    const float* g2     = (const float*)d_in[17];
    const float* beta2  = (const float*)d_in[18];
    const float* m2     = (const float*)d_in[19];
    const float* v2     = (const float*)d_in[20];
    const float* clsW   = (const float*)d_in[21];
    const float* clsb   = (const float*)d_in[22];
    float* out = (float*)d_out;

    // workspace layout (all 16B-aligned)
    char* ws = (char*)d_ws;
    const size_t A_bytes     = (size_t)N_NODES * KDIM * 2;   // 51,200,000
    const size_t elist_bytes = (size_t)E_EDGES * 4;          //  3,200,000
    const size_t offs_pad    = 200064;
    const size_t cnt_bytes   = 200000;
    ushort_t* A      = (ushort_t*)(ws);
    int*      elist  = (int*)(ws + A_bytes);
    int*      offs   = (int*)(ws + A_bytes + elist_bytes);
    int*      cnt    = (int*)(ws + A_bytes + elist_bytes + offs_pad);
    char*     p      = ws + A_bytes + elist_bytes + offs_pad + cnt_bytes;
    int*      aux    = (int*)p;            p += 1024;
    int*      bstart = (int*)p;            p += 1088;
    ushort_t* Wf1    = (ushort_t*)p;       p += 131072;
    ushort_t* Wf2    = (ushort_t*)p;       p += 131072;
    float*    sc1    = (float*)p;          p += 512;
    float*    sh1    = (float*)p;          p += 512;
    float*    sc2    = (float*)p;          p += 512;
    float*    sh2    = (float*)p;          p += 512;

    const int TB = 256;

    hipMemsetAsync(cnt, 0, (size_t)N_NODES * 4, stream);

    // x embeddings (bf16) -> A[n][3]
    build_x_kernel<<<(N_NODES * 16 + TB - 1) / TB, TB, 0, stream>>>(x_idx, se, ce, pe, A);

    // CSR by dst + batch bounds + weight/BN prepack
    count_dst_kernel<<<(E_EDGES + TB - 1) / TB, TB, 0, stream>>>(eidx, cnt);
    scan1_kernel<<<SCAN_BLOCKS, 256, 0, stream>>>(cnt, offs, aux);
    scan2_kernel<<<1, 256, 0, stream>>>(aux);
    scan3_kernel<<<SCAN_BLOCKS, 256, 0, stream>>>(offs, aux);
    fill_kernel<<<(E_EDGES + TB - 1) / TB, TB, 0, stream>>>(eidx, etype, offs, cnt, elist);
    bounds_kernel<<<2, 256, 0, stream>>>(batch, bstart);
    prepack_w_kernel<<<64, 256, 0, stream>>>(W1, root1, W2, root2, Wf1, Wf2);
    bn_prep_kernel<<<1, 256, 0, stream>>>(b1, g1, beta1, m1, v1,
                                          b2, g2, beta2, m2, v2,
                                          sc1, sh1, sc2, sh2);

    // ----- layer 1
    agg_kernel<<<(N_NODES + 15) / 16, 256, 0, stream>>>(A, offs, elist, A);
    gemm_mfma_kernel<<<(N_NODES + 63) / 64, 256, 0, stream>>>(A, Wf1, sc1, sh1, A);

    // ----- layer 2
    agg_kernel<<<(N_NODES + 15) / 16, 256, 0, stream>>>(A, offs, elist, A);
    gemm_mfma_kernel<<<(N_NODES + 63) / 64, 256, 0, stream>>>(A, Wf2, sc2, sh2, A);

    // ----- fused global mean pool + classifier
    pool_cls_kernel<<<BATCHES, 256, 0, stream>>>(A + 3 * DH, bstart, clsW, clsb, out);
}